// Round 8
// baseline (1163.552 us; speedup 1.0000x reference)
//
#include <hip/hip_runtime.h>
#include <math.h>

namespace {

constexpr int NN  = 50000;   // nodes
constexpr int NE  = 800000;  // edges
constexpr int FIN = 128;     // in features
constexpr int CH  = 96;      // conv hidden
constexpr int LH  = 64;      // lin hidden
constexpr int NC  = 10;      // classes
constexpr int NG  = 128;     // graphs
constexpr int NB_NODES = (NN + 255) / 256;  // 196 blocks over nodes

typedef unsigned short u16;
typedef __attribute__((ext_vector_type(8))) unsigned short ushort8;

__device__ __forceinline__ int round8(int c) { return (c + 7) & ~7; }

// ---------------- graph-structure build (once per call) ----------------

__global__ void k_init(int* __restrict__ cnt) {
  int i = blockIdx.x * 256 + threadIdx.x;
  if (i < NN) cnt[i] = 0;
}

// one int atomic per edge; remember the slot so k_fill needs no atomic
__global__ void k_count(const int* __restrict__ ei, int* __restrict__ cnt,
                        u16* __restrict__ my_slot) {
  int e = blockIdx.x * 256 + threadIdx.x;
  if (e < NE) {
    int c = ei[NE + e];  // col (destination)
    my_slot[e] = (u16)atomicAdd(&cnt[c], 1);
  }
}

// scan of ROUNDED counts (each node's segment padded to a multiple of 8)
__global__ void k_scan1(const int* __restrict__ cnt, int* __restrict__ incl,
                        int* __restrict__ bsum) {
  __shared__ int s[256];
  int t = threadIdx.x, i = blockIdx.x * 256 + t;
  s[t] = (i < NN) ? round8(cnt[i]) : 0;
  for (int off = 1; off < 256; off <<= 1) {
    __syncthreads();
    int u = (t >= off) ? s[t - off] : 0;
    __syncthreads();
    s[t] += u;
  }
  if (i < NN) incl[i] = s[t];
  if (t == 255) bsum[blockIdx.x] = s[255];
}

__global__ void k_scan2(int* __restrict__ bsum) {
  __shared__ int s[256];
  int t = threadIdx.x;
  int v = (t < NB_NODES) ? bsum[t] : 0;
  s[t] = v;
  for (int off = 1; off < 256; off <<= 1) {
    __syncthreads();
    int u = (t >= off) ? s[t - off] : 0;
    __syncthreads();
    s[t] += u;
  }
  if (t < NB_NODES) bsum[t] = s[t] - v;  // exclusive block offsets
}

__global__ void k_scan3(const int* __restrict__ cnt, int* __restrict__ offs,
                        const int* __restrict__ bsum) {
  int t = threadIdx.x, i = blockIdx.x * 256 + t;
  if (i < NN) offs[i] = offs[i] - round8(cnt[i]) + bsum[blockIdx.x];
}

// atomic-free CSR fill: srcs (u16) + raw edge weight (f32)
__global__ void k_fill(const int* __restrict__ ei, const float* __restrict__ ew,
                       const int* __restrict__ offs,
                       const u16* __restrict__ my_slot,
                       u16* __restrict__ srcs, float* __restrict__ wts) {
  int e = blockIdx.x * 256 + threadIdx.x;
  if (e < NE) {
    int r = ei[e], c = ei[NE + e];
    int slot = offs[c] + (int)my_slot[e];
    srcs[slot] = (u16)r;
    wts[slot] = ew[e];
  }
}

// fill pad slots with (src=0, w=0), round cnt up to multiple of 8
__global__ void k_pad(int* __restrict__ cnt, const int* __restrict__ offs,
                      u16* __restrict__ srcs, float* __restrict__ wts) {
  int n = blockIdx.x * 256 + threadIdx.x;
  if (n < NN) {
    int c = cnt[n], cp = round8(c), base = offs[n];
    for (int j = base + c; j < base + cp; ++j) { srcs[j] = 0; wts[j] = 0.f; }
    cnt[n] = cp;
  }
}

// ---- degree-bucket counting sort: perm groups nodes of equal padded degree ----

__global__ void k_hist0(int* __restrict__ hist, int* __restrict__ cur) {
  int t = threadIdx.x;
  if (t < 64) { hist[t] = 0; cur[t] = 0; }
}

__global__ void k_hist(const int* __restrict__ cnt, int* __restrict__ hist) {
  int n = blockIdx.x * 256 + threadIdx.x;
  if (n < NN) atomicAdd(&hist[min(cnt[n] >> 3, 63)], 1);
}

__global__ void k_bscan(const int* __restrict__ hist, int* __restrict__ bbase) {
  __shared__ int s[64];
  int t = threadIdx.x;
  s[t] = hist[t];
  for (int off = 1; off < 64; off <<= 1) {
    __syncthreads();
    int u = (t >= off) ? s[t - off] : 0;
    __syncthreads();
    s[t] += u;
  }
  __syncthreads();
  bbase[t] = s[t] - hist[t];  // exclusive
}

__global__ void k_perm(const int* __restrict__ cnt, const int* __restrict__ bbase,
                       int* __restrict__ cur, int* __restrict__ perm) {
  int n = blockIdx.x * 256 + threadIdx.x;
  if (n < NN) {
    int b = min(cnt[n] >> 3, 63);
    int r = atomicAdd(&cur[b], 1);
    perm[bbase[b] + r] = n;  // order within bucket arbitrary; output value-invariant
  }
}

// dinv[n] = rsqrt(1 + sum of in-edge weights); degree-sorted for uniform waves
__global__ void k_deg(const int* __restrict__ perm, const int* __restrict__ offs,
                      const int* __restrict__ cnt, const float* __restrict__ wts,
                      float* __restrict__ dinv) {
  int i = blockIdx.x * 256 + threadIdx.x;
  if (i < NN) {
    int n = perm[i];
    int s = offs[n], e = s + cnt[n];
    float d0 = 1.0f, d1 = 0.f, d2 = 0.f, d3 = 0.f;  // self-loop weight 1
    for (int j = s; j < e; j += 4) {
      d0 += wts[j]; d1 += wts[j + 1]; d2 += wts[j + 2]; d3 += wts[j + 3];
    }
    dinv[n] = 1.0f / sqrtf((d0 + d1) + (d2 + d3));  // >= 1 always
  }
}

// rewrite wts with final coefficient dinv[src]*ew*dinv[dst] (pads stay 0)
__global__ void k_scale(const int* __restrict__ perm, const int* __restrict__ offs,
                        const int* __restrict__ cnt, const float* __restrict__ dinv,
                        const u16* __restrict__ srcs, float* __restrict__ wts) {
  int i = blockIdx.x * 256 + threadIdx.x;
  if (i < NN) {
    int n = perm[i];
    int s = offs[n], e = s + cnt[n];
    float dn = dinv[n];
    for (int j = s; j < e; j += 4) {
      int s0 = srcs[j], s1 = srcs[j + 1], s2 = srcs[j + 2], s3 = srcs[j + 3];
      float v0 = dinv[s0], v1 = dinv[s1], v2 = dinv[s2], v3 = dinv[s3];
      wts[j]     = v0 * wts[j] * dn;
      wts[j + 1] = v1 * wts[j + 1] * dn;
      wts[j + 2] = v2 * wts[j + 2] * dn;
      wts[j + 3] = v3 * wts[j + 3] * dn;
    }
  }
}

// ---------------- GEMM: Y[slice][NN][12] = X @ W, sliced output ----------------
// SLICED_IN: X is also [8][NN][12] (previous layer's H). 64-node tile, 128 thr.

template <int K, bool SLICED_IN>
__global__ __launch_bounds__(128) void k_gemm(const float* __restrict__ X,
                                              const float* __restrict__ Wg,
                                              float* __restrict__ Y) {
  constexpr int KC  = 32;
  constexpr int LDX = KC + 1;  // stride-33 rows -> conflict-free x reads
  __shared__ float sX[64 * LDX];
  __shared__ float sW[KC * CH];
  int tid = threadIdx.x;
  int n0 = blockIdx.x * 64;
  int a = tid >> 3, cg = tid & 7;
  float acc[4][12];
#pragma unroll
  for (int j = 0; j < 4; ++j)
#pragma unroll
    for (int i = 0; i < 12; ++i) acc[j][i] = 0.f;

  for (int kc = 0; kc < K; kc += KC) {
    __syncthreads();  // protect previous chunk's LDS reads
    {
      const float4* src = (const float4*)(Wg + (size_t)kc * CH);
      float4* dst = (float4*)sW;
#pragma unroll
      for (int i = 0; i < 6; ++i) dst[tid + i * 128] = src[tid + i * 128];
    }
    {
#pragma unroll
      for (int p = 0; p < 4; ++p) {
        int i = tid + p * 128;
        int r = i >> 3, c = i & 7;
        int n = n0 + r;
        float4 v = make_float4(0.f, 0.f, 0.f, 0.f);
        if (n < NN) {
          if (!SLICED_IN) {
            v = *(const float4*)(X + (size_t)n * K + kc + c * 4);
          } else {
            int qq = (kc >> 2) + c;          // global float4 index 0..23
            int sl = qq / 3, part = qq - sl * 3;
            v = *(const float4*)(X + ((size_t)sl * NN + n) * 12 + part * 4);
          }
        }
        float* d = &sX[r * LDX + c * 4];
        d[0] = v.x; d[1] = v.y; d[2] = v.z; d[3] = v.w;
      }
    }
    __syncthreads();
#pragma unroll 8
    for (int k = 0; k < KC; ++k) {
      float xv[4];
#pragma unroll
      for (int j = 0; j < 4; ++j) xv[j] = sX[(a + j * 16) * LDX + k];
      const float4* wr = (const float4*)&sW[k * CH + cg * 12];
      float4 w0 = wr[0], w1 = wr[1], w2 = wr[2];
#pragma unroll
      for (int j = 0; j < 4; ++j) {
        acc[j][0] += xv[j] * w0.x; acc[j][1]  += xv[j] * w0.y;
        acc[j][2] += xv[j] * w0.z; acc[j][3]  += xv[j] * w0.w;
        acc[j][4] += xv[j] * w1.x; acc[j][5]  += xv[j] * w1.y;
        acc[j][6] += xv[j] * w1.z; acc[j][7]  += xv[j] * w1.w;
        acc[j][8] += xv[j] * w2.x; acc[j][9]  += xv[j] * w2.y;
        acc[j][10] += xv[j] * w2.z; acc[j][11] += xv[j] * w2.w;
      }
    }
  }
#pragma unroll
  for (int j = 0; j < 4; ++j) {
    int n = n0 + a + j * 16;
    if (n < NN) {
      float* yo = Y + ((size_t)cg * NN + n) * 12;  // sliced layout
      *(float4*)(yo + 0) = make_float4(acc[j][0], acc[j][1], acc[j][2], acc[j][3]);
      *(float4*)(yo + 4) = make_float4(acc[j][4], acc[j][5], acc[j][6], acc[j][7]);
      *(float4*)(yo + 8) = make_float4(acc[j][8], acc[j][9], acc[j][10], acc[j][11]);
    }
  }
}

// ---------------- aggregation (per feature-slice, XCD-affine, degree-sorted) ----
// grid = 8 slices x 782 node-blocks; slice = blockIdx % 8 -> lands on XCD (slice).
// Slice Y region = 2.4MB -> L2-resident per XCD. Nodes taken via degree-sorted
// perm so each wave's edge-loop trip count is uniform. H also sliced [8][NN][12].

template <bool RELU>
__global__ __launch_bounds__(192) void k_agg(const float* __restrict__ Yall,
                                             const int* __restrict__ perm,
                                             const int* __restrict__ offs,
                                             const int* __restrict__ cnt,
                                             const u16* __restrict__ srcs,
                                             const float* __restrict__ wts,
                                             const float* __restrict__ dinv,
                                             const float* __restrict__ bias,
                                             float* __restrict__ H) {
  int slice = blockIdx.x & 7;
  int nb = blockIdx.x >> 3;
  int tid = threadIdx.x;
  int nl = tid / 3;        // node slot 0..63
  int fq = tid - nl * 3;   // float4 chunk 0..2
  int nid = nb * 64 + nl;
  if (nid >= NN) return;
  int n = perm[nid];
  const float4* Ys = (const float4*)(Yall + (size_t)slice * NN * 12);
  float d = dinv[n];
  float sc = d * d;
  float4 sv = Ys[(size_t)n * 3 + fq];
  float ax = sc * sv.x, ay = sc * sv.y, az = sc * sv.z, aw = sc * sv.w;
  int s = offs[n], e = s + cnt[n];  // multiple of 8, 16B-aligned starts
  for (int j = s; j < e; j += 8) {
    ushort8 s8 = *(const ushort8*)&srcs[j];
    float4 c0 = *(const float4*)&wts[j];
    float4 c1 = *(const float4*)&wts[j + 4];
    float4 yv[8];
#pragma unroll
    for (int u = 0; u < 8; ++u) yv[u] = Ys[(size_t)s8[u] * 3 + fq];
    float cf[8] = {c0.x, c0.y, c0.z, c0.w, c1.x, c1.y, c1.z, c1.w};
#pragma unroll
    for (int u = 0; u < 8; ++u) {
      ax += cf[u] * yv[u].x; ay += cf[u] * yv[u].y;
      az += cf[u] * yv[u].z; aw += cf[u] * yv[u].w;
    }
  }
  float4 bv = *(const float4*)(bias + slice * 12 + fq * 4);
  ax += bv.x; ay += bv.y; az += bv.z; aw += bv.w;
  if (RELU) {
    ax = fmaxf(ax, 0.f); ay = fmaxf(ay, 0.f);
    az = fmaxf(az, 0.f); aw = fmaxf(aw, 0.f);
  }
  *(float4*)(H + ((size_t)slice * NN + n) * 12 + fq * 4) = make_float4(ax, ay, az, aw);
}

// ---------------- pool + MLP ----------------

__global__ void k_gstart(const int* __restrict__ batch, int* __restrict__ gstart) {
  int i = blockIdx.x * 256 + threadIdx.x;
  if (i < NN) {
    int g = batch[i];
    if (i == 0 || batch[i - 1] != g) gstart[g] = i;
    if (i == NN - 1) gstart[NG] = NN;
  }
}

// H is sliced [8][NN][12]; feature f lives at H[(f/12)*NN + n][f%12]
__global__ void k_pool(const float* __restrict__ H, const int* __restrict__ gstart,
                       float* __restrict__ part) {
  int g = blockIdx.x, q = blockIdx.y, f = threadIdx.x;
  if (f >= CH) return;
  const float* Hf = H + (size_t)(f / 12) * NN * 12 + (f % 12);
  int s = gstart[g], e = gstart[g + 1];
  int len = e - s;
  int a = s + (int)(((long long)len * q) / 4);
  int b = s + (int)(((long long)len * (q + 1)) / 4);
  float m = -INFINITY;
  for (int n = a; n < b; ++n) m = fmaxf(m, Hf[(size_t)n * 12]);
  part[(g * 4 + q) * CH + f] = m;
}

__global__ void k_mlp(const float* __restrict__ part, const float* __restrict__ Wl1,
                      const float* __restrict__ bl1, const float* __restrict__ Wl2,
                      const float* __restrict__ bl2, float* __restrict__ out) {
  __shared__ float p[CH];
  __shared__ float hs[LH];
  int g = blockIdx.x, t = threadIdx.x;
  if (t < CH) {
    float m = part[(g * 4 + 0) * CH + t];
    m = fmaxf(m, part[(g * 4 + 1) * CH + t]);
    m = fmaxf(m, part[(g * 4 + 2) * CH + t]);
    m = fmaxf(m, part[(g * 4 + 3) * CH + t]);
    p[t] = fmaxf(m, 0.f);  // relu(max) == max(relu)
  }
  __syncthreads();
  if (t < LH) {
    float a = bl1[t];
#pragma unroll 4
    for (int k = 0; k < CH; ++k) a += p[k] * Wl1[k * LH + t];
    hs[t] = fmaxf(a, 0.f);
  }
  __syncthreads();
  if (t < NC) {
    float a = bl2[t];
#pragma unroll 4
    for (int k = 0; k < LH; ++k) a += hs[k] * Wl2[k * NC + t];
    out[g * NC + t] = a;
  }
}

}  // namespace

extern "C" void kernel_launch(void* const* d_in, const int* in_sizes, int n_in,
                              void* d_out, int out_size, void* d_ws, size_t ws_size,
                              hipStream_t stream) {
  const float* x   = (const float*)d_in[0];
  const int*   ei  = (const int*)d_in[1];
  const float* ew  = (const float*)d_in[2];
  const int*   bat = (const int*)d_in[3];
  const float* W1  = (const float*)d_in[4];
  const float* b1  = (const float*)d_in[5];
  const float* W2  = (const float*)d_in[6];
  const float* b2  = (const float*)d_in[7];
  const float* W3  = (const float*)d_in[8];
  const float* b3  = (const float*)d_in[9];
  const float* Wl1 = (const float*)d_in[10];
  const float* bl1 = (const float*)d_in[11];
  const float* Wl2 = (const float*)d_in[12];
  const float* bl2 = (const float*)d_in[13];
  float* out = (float*)d_out;

  // workspace carve-up (256B aligned)
  char* base = (char*)d_ws;
  size_t o = 0;
  auto carve = [&](size_t bytes) {
    char* p = base + o;
    o = (o + bytes + 255) & ~(size_t)255;
    return p;
  };
  constexpr size_t NEP = (size_t)NE + 8 * (size_t)NN;  // padded CSR capacity
  float* dinv    = (float*)carve(NN * 4);
  int*   cnt     = (int*)carve(NN * 4);
  int*   offs    = (int*)carve(NN * 4);
  u16*   my_slot = (u16*)carve((size_t)NE * 2);
  int*   bsum    = (int*)carve(256 * 4);
  int*   gstart  = (int*)carve((NG + 1) * 4);
  float* part    = (float*)carve(NG * 4 * CH * 4);
  int*   hist    = (int*)carve(64 * 4);
  int*   curb    = (int*)carve(64 * 4);
  int*   bbase   = (int*)carve(64 * 4);
  int*   perm    = (int*)carve(NN * 4);
  u16*   srcs    = (u16*)carve(NEP * 2);
  float* wts     = (float*)carve(NEP * 4);
  float* Y       = (float*)carve((size_t)NN * CH * 4);  // sliced [8][NN][12]
  float* H       = (float*)carve((size_t)NN * CH * 4);  // sliced [8][NN][12]
  (void)ws_size; (void)n_in; (void)in_sizes; (void)out_size;

  const int GB_N = NB_NODES;                 // 196
  const int GB_E = (NE + 255) / 256;         // 3125
  const int GB_G = (NN + 63) / 64;           // 782 gemm blocks
  const int GB_A = 8 * ((NN + 63) / 64);     // 8 slices x 782 node-blocks

  // graph structure (shared by all 3 conv layers)
  k_init<<<GB_N, 256, 0, stream>>>(cnt);
  k_count<<<GB_E, 256, 0, stream>>>(ei, cnt, my_slot);
  k_scan1<<<GB_N, 256, 0, stream>>>(cnt, offs, bsum);
  k_scan2<<<1, 256, 0, stream>>>(bsum);
  k_scan3<<<GB_N, 256, 0, stream>>>(cnt, offs, bsum);
  k_fill<<<GB_E, 256, 0, stream>>>(ei, ew, offs, my_slot, srcs, wts);
  k_pad<<<GB_N, 256, 0, stream>>>(cnt, offs, srcs, wts);
  // degree-bucket sort
  k_hist0<<<1, 64, 0, stream>>>(hist, curb);
  k_hist<<<GB_N, 256, 0, stream>>>(cnt, hist);
  k_bscan<<<1, 64, 0, stream>>>(hist, bbase);
  k_perm<<<GB_N, 256, 0, stream>>>(cnt, bbase, curb, perm);
  // normalization coefficients
  k_deg<<<GB_N, 256, 0, stream>>>(perm, offs, cnt, wts, dinv);
  k_scale<<<GB_N, 256, 0, stream>>>(perm, offs, cnt, dinv, srcs, wts);

  // layer 1 (dense input x)
  k_gemm<FIN, false><<<GB_G, 128, 0, stream>>>(x, W1, Y);
  k_agg<true><<<GB_A, 192, 0, stream>>>(Y, perm, offs, cnt, srcs, wts, dinv, b1, H);
  // layer 2 (sliced input H)
  k_gemm<CH, true><<<GB_G, 128, 0, stream>>>(H, W2, Y);
  k_agg<true><<<GB_A, 192, 0, stream>>>(Y, perm, offs, cnt, srcs, wts, dinv, b2, H);
  // layer 3
  k_gemm<CH, true><<<GB_G, 128, 0, stream>>>(H, W3, Y);
  k_agg<false><<<GB_A, 192, 0, stream>>>(Y, perm, offs, cnt, srcs, wts, dinv, b3, H);

  // pool + MLP
  k_gstart<<<GB_N, 256, 0, stream>>>(bat, gstart);
  k_pool<<<dim3(NG, 4), 128, 0, stream>>>(H, gstart, part);
  k_mlp<<<NG, 128, 0, stream>>>(part, Wl1, bl1, Wl2, bl2, out);
}

// Round 9
// 355.822 us; speedup vs baseline: 3.2700x; 3.2700x over previous
//
#include <hip/hip_runtime.h>
#include <math.h>

namespace {

constexpr int NN  = 50000;   // nodes
constexpr int NE  = 800000;  // edges
constexpr int FIN = 128;     // in features
constexpr int CH  = 96;      // conv hidden
constexpr int LH  = 64;      // lin hidden
constexpr int NC  = 10;      // classes
constexpr int NG  = 128;     // graphs
constexpr int NBLK = (NN + 255) / 256;  // 196 blocks over nodes

typedef unsigned short u16;
typedef __attribute__((ext_vector_type(8))) unsigned short ushort8;

__device__ __forceinline__ int round8(int c) { return (c + 7) & ~7; }
__device__ __forceinline__ int bucket_of(int craw) { return min(round8(craw) >> 3, 63); }

// ---------------- graph-structure build (once per call) ----------------

__global__ void k_init(int* __restrict__ cnt) {
  int i = blockIdx.x * 256 + threadIdx.x;
  if (i < NN) cnt[i] = 0;
}

// one int atomic per edge; remember the slot so k_fill needs no atomic
__global__ void k_count(const int* __restrict__ ei, int* __restrict__ cnt,
                        u16* __restrict__ my_slot) {
  int e = blockIdx.x * 256 + threadIdx.x;
  if (e < NE) {
    int c = ei[NE + e];  // col (destination)
    my_slot[e] = (u16)atomicAdd(&cnt[c], 1);
  }
}

// ---- contention-free degree-bucket counting sort (rank = sorted position) ----

__global__ void k_bhist(const int* __restrict__ cnt, int* __restrict__ hist2d) {
  __shared__ int lh[64];
  int t = threadIdx.x;
  if (t < 64) lh[t] = 0;
  __syncthreads();
  int n = blockIdx.x * 256 + t;
  if (n < NN) atomicAdd(&lh[bucket_of(cnt[n])], 1);  // LDS atomic
  __syncthreads();
  if (t < 64) hist2d[t * NBLK + blockIdx.x] = lh[t];
}

// exclusive scan of hist2d[64*NBLK] in place; 64*196 = 12544 = 256*49
__global__ void k_gscan(int* __restrict__ h) {
  __shared__ int s[256];
  constexpr int CHUNK = (64 * NBLK) / 256;  // 49
  int t = threadIdx.x;
  int base = t * CHUNK;
  int sum = 0;
  for (int i = 0; i < CHUNK; ++i) sum += h[base + i];
  s[t] = sum;
  for (int off = 1; off < 256; off <<= 1) {
    __syncthreads();
    int u = (t >= off) ? s[t - off] : 0;
    __syncthreads();
    s[t] += u;
  }
  __syncthreads();
  int run = s[t] - sum;  // exclusive base for this chunk
  for (int i = 0; i < CHUNK; ++i) {
    int v = h[base + i];
    h[base + i] = run;
    run += v;
  }
}

__global__ void k_place(const int* __restrict__ cnt, const int* __restrict__ base2d,
                        int* __restrict__ perm, int* __restrict__ irank,
                        int* __restrict__ cntr, int* __restrict__ craw) {
  __shared__ int lc[64];
  int t = threadIdx.x;
  if (t < 64) lc[t] = 0;
  __syncthreads();
  int n = blockIdx.x * 256 + t;
  if (n < NN) {
    int c = cnt[n];
    int b = bucket_of(c);
    int r = atomicAdd(&lc[b], 1);  // LDS atomic: rank within (block, bucket)
    int rank = base2d[b * NBLK + blockIdx.x] + r;
    perm[rank] = n;
    irank[n] = rank;
    cntr[rank] = round8(c);
    craw[rank] = c;
  }
}

// ---- rank-space CSR offsets: exclusive scan of padded counts ----

__global__ void k_scan1(const int* __restrict__ cntr, int* __restrict__ incl,
                        int* __restrict__ bsum) {
  __shared__ int s[256];
  int t = threadIdx.x, i = blockIdx.x * 256 + t;
  s[t] = (i < NN) ? cntr[i] : 0;
  for (int off = 1; off < 256; off <<= 1) {
    __syncthreads();
    int u = (t >= off) ? s[t - off] : 0;
    __syncthreads();
    s[t] += u;
  }
  if (i < NN) incl[i] = s[t];
  if (t == 255) bsum[blockIdx.x] = s[255];
}

__global__ void k_scan2(int* __restrict__ bsum) {
  __shared__ int s[256];
  int t = threadIdx.x;
  int v = (t < NBLK) ? bsum[t] : 0;
  s[t] = v;
  for (int off = 1; off < 256; off <<= 1) {
    __syncthreads();
    int u = (t >= off) ? s[t - off] : 0;
    __syncthreads();
    s[t] += u;
  }
  if (t < NBLK) bsum[t] = s[t] - v;  // exclusive block offsets
}

__global__ void k_scan3(const int* __restrict__ cntr, int* __restrict__ offs,
                        const int* __restrict__ bsum) {
  int t = threadIdx.x, i = blockIdx.x * 256 + t;
  if (i < NN) offs[i] = offs[i] - cntr[i] + bsum[blockIdx.x];  // incl -> excl + base
}

// atomic-free CSR fill in RANK space: srcs stores source RANK (u16)
__global__ void k_fill(const int* __restrict__ ei, const float* __restrict__ ew,
                       const int* __restrict__ offs_r, const int* __restrict__ irank,
                       const u16* __restrict__ my_slot,
                       u16* __restrict__ srcs, float* __restrict__ wts) {
  int e = blockIdx.x * 256 + threadIdx.x;
  if (e < NE) {
    int r = ei[e], c = ei[NE + e];
    int slot = offs_r[irank[c]] + (int)my_slot[e];
    srcs[slot] = (u16)irank[r];
    wts[slot] = ew[e];
  }
}

// fill pad slots with (src=0, w=0) — weight 0 => contributes nothing downstream
__global__ void k_pad(const int* __restrict__ craw, const int* __restrict__ cntr,
                      const int* __restrict__ offs_r,
                      u16* __restrict__ srcs, float* __restrict__ wts) {
  int i = blockIdx.x * 256 + threadIdx.x;
  if (i < NN) {
    int base = offs_r[i];
    for (int j = base + craw[i]; j < base + cntr[i]; ++j) { srcs[j] = 0; wts[j] = 0.f; }
  }
}

// dinv_r[rank] = rsqrt(1 + sum of in-edge weights); contiguous rank streaming
__global__ void k_deg(const int* __restrict__ offs_r, const int* __restrict__ cntr,
                      const float* __restrict__ wts, float* __restrict__ dinv_r) {
  int i = blockIdx.x * 256 + threadIdx.x;
  if (i < NN) {
    int s = offs_r[i], e = s + cntr[i];
    float d0 = 1.0f, d1 = 0.f, d2 = 0.f, d3 = 0.f;  // self-loop weight 1
    for (int j = s; j < e; j += 4) {
      d0 += wts[j]; d1 += wts[j + 1]; d2 += wts[j + 2]; d3 += wts[j + 3];
    }
    dinv_r[i] = 1.0f / sqrtf((d0 + d1) + (d2 + d3));  // >= 1 always
  }
}

// wts[j] = dinv_r[src_rank] * ew * dinv_r[dst_rank]  (pads stay 0)
__global__ void k_scale(const int* __restrict__ offs_r, const int* __restrict__ cntr,
                        const float* __restrict__ dinv_r,
                        const u16* __restrict__ srcs, float* __restrict__ wts) {
  int i = blockIdx.x * 256 + threadIdx.x;
  if (i < NN) {
    int s = offs_r[i], e = s + cntr[i];
    float dn = dinv_r[i];
    for (int j = s; j < e; j += 4) {
      int s0 = srcs[j], s1 = srcs[j + 1], s2 = srcs[j + 2], s3 = srcs[j + 3];
      float v0 = dinv_r[s0], v1 = dinv_r[s1], v2 = dinv_r[s2], v3 = dinv_r[s3];
      wts[j]     = v0 * wts[j] * dn;
      wts[j + 1] = v1 * wts[j + 1] * dn;
      wts[j + 2] = v2 * wts[j + 2] * dn;
      wts[j + 3] = v3 * wts[j + 3] * dn;
    }
  }
}

// ---------------- GEMM: Y[slice][rank][12] = X @ W, sliced rank-space output ----
// PERM_DENSE: X is dense node-space [NN][K], row looked up via perm (layer 1).
// else: X is sliced rank-space [8][NN][12] (layers 2,3; K == CH).

template <int K, bool PERM_DENSE>
__global__ __launch_bounds__(128) void k_gemm(const float* __restrict__ X,
                                              const float* __restrict__ Wg,
                                              float* __restrict__ Y,
                                              const int* __restrict__ perm) {
  constexpr int KC  = 32;
  constexpr int LDX = KC + 1;  // stride-33 rows -> conflict-free x reads
  __shared__ float sX[64 * LDX];
  __shared__ float sW[KC * CH];
  __shared__ int sPerm[64];
  int tid = threadIdx.x;
  int n0 = blockIdx.x * 64;
  int a = tid >> 3, cg = tid & 7;
  if (PERM_DENSE && tid < 64) {
    int nr = n0 + tid;
    sPerm[tid] = (nr < NN) ? perm[nr] : -1;
  }
  float acc[4][12];
#pragma unroll
  for (int j = 0; j < 4; ++j)
#pragma unroll
    for (int i = 0; i < 12; ++i) acc[j][i] = 0.f;

  for (int kc = 0; kc < K; kc += KC) {
    __syncthreads();  // protects prev-chunk LDS reads and sPerm store
    {
      const float4* src = (const float4*)(Wg + (size_t)kc * CH);
      float4* dst = (float4*)sW;
#pragma unroll
      for (int i = 0; i < 6; ++i) dst[tid + i * 128] = src[tid + i * 128];
    }
    {
#pragma unroll
      for (int p = 0; p < 4; ++p) {
        int i = tid + p * 128;
        int r = i >> 3, c = i & 7;
        float4 v = make_float4(0.f, 0.f, 0.f, 0.f);
        if (PERM_DENSE) {
          int row = sPerm[r];
          if (row >= 0) v = *(const float4*)(X + (size_t)row * K + kc + c * 4);
        } else {
          int n = n0 + r;
          if (n < NN) {
            int qq = (kc >> 2) + c;          // global float4 index 0..23
            int sl = qq / 3, part = qq - sl * 3;
            v = *(const float4*)(X + ((size_t)sl * NN + n) * 12 + part * 4);
          }
        }
        float* d = &sX[r * LDX + c * 4];
        d[0] = v.x; d[1] = v.y; d[2] = v.z; d[3] = v.w;
      }
    }
    __syncthreads();
#pragma unroll 8
    for (int k = 0; k < KC; ++k) {
      float xv[4];
#pragma unroll
      for (int j = 0; j < 4; ++j) xv[j] = sX[(a + j * 16) * LDX + k];
      const float4* wr = (const float4*)&sW[k * CH + cg * 12];
      float4 w0 = wr[0], w1 = wr[1], w2 = wr[2];
#pragma unroll
      for (int j = 0; j < 4; ++j) {
        acc[j][0] += xv[j] * w0.x; acc[j][1]  += xv[j] * w0.y;
        acc[j][2] += xv[j] * w0.z; acc[j][3]  += xv[j] * w0.w;
        acc[j][4] += xv[j] * w1.x; acc[j][5]  += xv[j] * w1.y;
        acc[j][6] += xv[j] * w1.z; acc[j][7]  += xv[j] * w1.w;
        acc[j][8] += xv[j] * w2.x; acc[j][9]  += xv[j] * w2.y;
        acc[j][10] += xv[j] * w2.z; acc[j][11] += xv[j] * w2.w;
      }
    }
  }
#pragma unroll
  for (int j = 0; j < 4; ++j) {
    int n = n0 + a + j * 16;  // rank
    if (n < NN) {
      float* yo = Y + ((size_t)cg * NN + n) * 12;  // sliced rank-space
      *(float4*)(yo + 0) = make_float4(acc[j][0], acc[j][1], acc[j][2], acc[j][3]);
      *(float4*)(yo + 4) = make_float4(acc[j][4], acc[j][5], acc[j][6], acc[j][7]);
      *(float4*)(yo + 8) = make_float4(acc[j][8], acc[j][9], acc[j][10], acc[j][11]);
    }
  }
}

// ---------------- aggregation (feature-sliced, XCD-affine, rank-space) ----------
// grid = 8 slices x 782 rank-blocks; slice = blockIdx % 8 -> lands on XCD (slice).
// Ranks are degree-sorted: uniform trip counts AND consecutive CSR segments.

template <bool RELU>
__global__ __launch_bounds__(192) void k_agg(const float* __restrict__ Yall,
                                             const int* __restrict__ offs_r,
                                             const int* __restrict__ cntr,
                                             const u16* __restrict__ srcs,
                                             const float* __restrict__ wts,
                                             const float* __restrict__ dinv_r,
                                             const float* __restrict__ bias,
                                             float* __restrict__ H) {
  int slice = blockIdx.x & 7;
  int nb = blockIdx.x >> 3;
  int tid = threadIdx.x;
  int nl = tid / 3;        // rank slot 0..63
  int fq = tid - nl * 3;   // float4 chunk 0..2
  int n = nb * 64 + nl;    // rank
  if (n >= NN) return;
  const float4* Ys = (const float4*)(Yall + (size_t)slice * NN * 12);
  float d = dinv_r[n];
  float sc = d * d;
  float4 sv = Ys[(size_t)n * 3 + fq];
  float ax = sc * sv.x, ay = sc * sv.y, az = sc * sv.z, aw = sc * sv.w;
  int s = offs_r[n], e = s + cntr[n];  // multiple of 8, aligned starts
  for (int j = s; j < e; j += 8) {
    ushort8 s8 = *(const ushort8*)&srcs[j];
    float4 c0 = *(const float4*)&wts[j];
    float4 c1 = *(const float4*)&wts[j + 4];
    float4 yv[8];
#pragma unroll
    for (int u = 0; u < 8; ++u) yv[u] = Ys[(size_t)s8[u] * 3 + fq];
    float cf[8] = {c0.x, c0.y, c0.z, c0.w, c1.x, c1.y, c1.z, c1.w};
#pragma unroll
    for (int u = 0; u < 8; ++u) {
      ax += cf[u] * yv[u].x; ay += cf[u] * yv[u].y;
      az += cf[u] * yv[u].z; aw += cf[u] * yv[u].w;
    }
  }
  float4 bv = *(const float4*)(bias + slice * 12 + fq * 4);
  ax += bv.x; ay += bv.y; az += bv.z; aw += bv.w;
  if (RELU) {
    ax = fmaxf(ax, 0.f); ay = fmaxf(ay, 0.f);
    az = fmaxf(az, 0.f); aw = fmaxf(aw, 0.f);
  }
  *(float4*)(H + ((size_t)slice * NN + n) * 12 + fq * 4) = make_float4(ax, ay, az, aw);
}

// ---------------- pool + MLP ----------------

__global__ void k_gstart(const int* __restrict__ batch, int* __restrict__ gstart) {
  int i = blockIdx.x * 256 + threadIdx.x;
  if (i < NN) {
    int g = batch[i];
    if (i == 0 || batch[i - 1] != g) gstart[g] = i;
    if (i == NN - 1) gstart[NG] = NN;
  }
}

// H sliced rank-space: feature f of node n at H[(f/12)*NN + irank[n]]*12 + f%12
__global__ void k_pool(const float* __restrict__ H, const int* __restrict__ gstart,
                       const int* __restrict__ irank, float* __restrict__ part) {
  int g = blockIdx.x, q = blockIdx.y, f = threadIdx.x;
  if (f >= CH) return;
  const float* Hf = H + (size_t)(f / 12) * NN * 12 + (f % 12);
  int s = gstart[g], e = gstart[g + 1];
  int len = e - s;
  int a = s + (int)(((long long)len * q) / 4);
  int b = s + (int)(((long long)len * (q + 1)) / 4);
  float m = -INFINITY;
  for (int n = a; n < b; ++n) m = fmaxf(m, Hf[(size_t)irank[n] * 12]);
  part[(g * 4 + q) * CH + f] = m;
}

__global__ void k_mlp(const float* __restrict__ part, const float* __restrict__ Wl1,
                      const float* __restrict__ bl1, const float* __restrict__ Wl2,
                      const float* __restrict__ bl2, float* __restrict__ out) {
  __shared__ float p[CH];
  __shared__ float hs[LH];
  int g = blockIdx.x, t = threadIdx.x;
  if (t < CH) {
    float m = part[(g * 4 + 0) * CH + t];
    m = fmaxf(m, part[(g * 4 + 1) * CH + t]);
    m = fmaxf(m, part[(g * 4 + 2) * CH + t]);
    m = fmaxf(m, part[(g * 4 + 3) * CH + t]);
    p[t] = fmaxf(m, 0.f);  // relu(max) == max(relu)
  }
  __syncthreads();
  if (t < LH) {
    float a = bl1[t];
#pragma unroll 4
    for (int k = 0; k < CH; ++k) a += p[k] * Wl1[k * LH + t];
    hs[t] = fmaxf(a, 0.f);
  }
  __syncthreads();
  if (t < NC) {
    float a = bl2[t];
#pragma unroll 4
    for (int k = 0; k < LH; ++k) a += hs[k] * Wl2[k * NC + t];
    out[g * NC + t] = a;
  }
}

}  // namespace

extern "C" void kernel_launch(void* const* d_in, const int* in_sizes, int n_in,
                              void* d_out, int out_size, void* d_ws, size_t ws_size,
                              hipStream_t stream) {
  const float* x   = (const float*)d_in[0];
  const int*   ei  = (const int*)d_in[1];
  const float* ew  = (const float*)d_in[2];
  const int*   bat = (const int*)d_in[3];
  const float* W1  = (const float*)d_in[4];
  const float* b1  = (const float*)d_in[5];
  const float* W2  = (const float*)d_in[6];
  const float* b2  = (const float*)d_in[7];
  const float* W3  = (const float*)d_in[8];
  const float* b3  = (const float*)d_in[9];
  const float* Wl1 = (const float*)d_in[10];
  const float* bl1 = (const float*)d_in[11];
  const float* Wl2 = (const float*)d_in[12];
  const float* bl2 = (const float*)d_in[13];
  float* out = (float*)d_out;

  // workspace carve-up (256B aligned)
  char* base = (char*)d_ws;
  size_t o = 0;
  auto carve = [&](size_t bytes) {
    char* p = base + o;
    o = (o + bytes + 255) & ~(size_t)255;
    return p;
  };
  constexpr size_t NEP = (size_t)NE + 8 * (size_t)NN;  // padded CSR capacity
  int*   cnt     = (int*)carve(NN * 4);
  u16*   my_slot = (u16*)carve((size_t)NE * 2);
  int*   hist2d  = (int*)carve(64 * NBLK * 4);
  int*   perm    = (int*)carve(NN * 4);
  int*   irank   = (int*)carve(NN * 4);
  int*   cntr    = (int*)carve(NN * 4);
  int*   craw    = (int*)carve(NN * 4);
  int*   offs_r  = (int*)carve(NN * 4);
  int*   bsum    = (int*)carve(256 * 4);
  float* dinv_r  = (float*)carve(NN * 4);
  int*   gstart  = (int*)carve((NG + 1) * 4);
  float* part    = (float*)carve(NG * 4 * CH * 4);
  u16*   srcs    = (u16*)carve(NEP * 2);
  float* wts     = (float*)carve(NEP * 4);
  float* Y       = (float*)carve((size_t)NN * CH * 4);  // sliced [8][NN][12]
  float* H       = (float*)carve((size_t)NN * CH * 4);  // sliced [8][NN][12]
  (void)ws_size; (void)n_in; (void)in_sizes; (void)out_size;

  const int GB_N = NBLK;                     // 196
  const int GB_E = (NE + 255) / 256;         // 3125
  const int GB_G = (NN + 63) / 64;           // 782 gemm blocks
  const int GB_A = 8 * ((NN + 63) / 64);     // 8 slices x 782 rank-blocks

  // graph structure (shared by all 3 conv layers)
  k_init<<<GB_N, 256, 0, stream>>>(cnt);
  k_count<<<GB_E, 256, 0, stream>>>(ei, cnt, my_slot);
  // degree-bucket counting sort (no contended global atomics)
  k_bhist<<<GB_N, 256, 0, stream>>>(cnt, hist2d);
  k_gscan<<<1, 256, 0, stream>>>(hist2d);
  k_place<<<GB_N, 256, 0, stream>>>(cnt, hist2d, perm, irank, cntr, craw);
  // rank-space CSR
  k_scan1<<<GB_N, 256, 0, stream>>>(cntr, offs_r, bsum);
  k_scan2<<<1, 256, 0, stream>>>(bsum);
  k_scan3<<<GB_N, 256, 0, stream>>>(cntr, offs_r, bsum);
  k_fill<<<GB_E, 256, 0, stream>>>(ei, ew, offs_r, irank, my_slot, srcs, wts);
  k_pad<<<GB_N, 256, 0, stream>>>(craw, cntr, offs_r, srcs, wts);
  // normalization coefficients (rank space)
  k_deg<<<GB_N, 256, 0, stream>>>(offs_r, cntr, wts, dinv_r);
  k_scale<<<GB_N, 256, 0, stream>>>(offs_r, cntr, dinv_r, srcs, wts);

  // layer 1 (dense node-space input x, perm-gathered)
  k_gemm<FIN, true><<<GB_G, 128, 0, stream>>>(x, W1, Y, perm);
  k_agg<true><<<GB_A, 192, 0, stream>>>(Y, offs_r, cntr, srcs, wts, dinv_r, b1, H);
  // layer 2 (sliced rank-space input H)
  k_gemm<CH, false><<<GB_G, 128, 0, stream>>>(H, W2, Y, perm);
  k_agg<true><<<GB_A, 192, 0, stream>>>(Y, offs_r, cntr, srcs, wts, dinv_r, b2, H);
  // layer 3
  k_gemm<CH, false><<<GB_G, 128, 0, stream>>>(H, W3, Y, perm);
  k_agg<false><<<GB_A, 192, 0, stream>>>(Y, offs_r, cntr, srcs, wts, dinv_r, b3, H);

  // pool + MLP
  k_gstart<<<GB_N, 256, 0, stream>>>(bat, gstart);
  k_pool<<<dim3(NG, 4), 128, 0, stream>>>(H, gstart, irank, part);
  k_mlp<<<NG, 128, 0, stream>>>(part, Wl1, bl1, Wl2, bl2, out);
}

// Round 10
// 315.866 us; speedup vs baseline: 3.6837x; 1.1265x over previous
//
#include <hip/hip_runtime.h>
#include <math.h>

namespace {

constexpr int NN  = 50000;   // nodes
constexpr int NE  = 800000;  // edges
constexpr int FIN = 128;     // in features
constexpr int CH  = 96;      // conv hidden
constexpr int LH  = 64;      // lin hidden
constexpr int NC  = 10;      // classes
constexpr int NG  = 128;     // graphs
constexpr int NBLK = (NN + 255) / 256;  // 196 blocks over nodes

typedef unsigned short u16;
typedef __attribute__((ext_vector_type(8))) unsigned short ushort8;
typedef __attribute__((ext_vector_type(4))) _Float16 half4;
typedef __attribute__((ext_vector_type(8))) _Float16 half8;

__device__ __forceinline__ int round8(int c) { return (c + 7) & ~7; }
__device__ __forceinline__ int bucket_of(int craw) { return min(round8(craw) >> 3, 63); }

// ---------------- graph-structure build (once per call) ----------------

__global__ void k_init(int* __restrict__ cnt) {
  int i = blockIdx.x * 256 + threadIdx.x;
  if (i < NN) cnt[i] = 0;
}

// one int atomic per edge; remember the slot so k_fill needs no atomic
__global__ void k_count(const int* __restrict__ ei, int* __restrict__ cnt,
                        u16* __restrict__ my_slot) {
  int e = blockIdx.x * 256 + threadIdx.x;
  if (e < NE) {
    int c = ei[NE + e];  // col (destination)
    my_slot[e] = (u16)atomicAdd(&cnt[c], 1);
  }
}

// ---- contention-free degree-bucket counting sort (rank = sorted position) ----

__global__ void k_bhist(const int* __restrict__ cnt, int* __restrict__ hist2d) {
  __shared__ int lh[64];
  int t = threadIdx.x;
  if (t < 64) lh[t] = 0;
  __syncthreads();
  int n = blockIdx.x * 256 + t;
  if (n < NN) atomicAdd(&lh[bucket_of(cnt[n])], 1);  // LDS atomic
  __syncthreads();
  if (t < 64) hist2d[t * NBLK + blockIdx.x] = lh[t];
}

// exclusive scan of hist2d[64*NBLK] in place; 64*196 = 12544 = 256*49
__global__ void k_gscan(int* __restrict__ h) {
  __shared__ int s[256];
  constexpr int CHUNK = (64 * NBLK) / 256;  // 49
  int t = threadIdx.x;
  int base = t * CHUNK;
  int sum = 0;
  for (int i = 0; i < CHUNK; ++i) sum += h[base + i];
  s[t] = sum;
  for (int off = 1; off < 256; off <<= 1) {
    __syncthreads();
    int u = (t >= off) ? s[t - off] : 0;
    __syncthreads();
    s[t] += u;
  }
  __syncthreads();
  int run = s[t] - sum;  // exclusive base for this chunk
  for (int i = 0; i < CHUNK; ++i) {
    int v = h[base + i];
    h[base + i] = run;
    run += v;
  }
}

__global__ void k_place(const int* __restrict__ cnt, const int* __restrict__ base2d,
                        int* __restrict__ perm, int* __restrict__ irank,
                        int* __restrict__ cntr, int* __restrict__ craw) {
  __shared__ int lc[64];
  int t = threadIdx.x;
  if (t < 64) lc[t] = 0;
  __syncthreads();
  int n = blockIdx.x * 256 + t;
  if (n < NN) {
    int c = cnt[n];
    int b = bucket_of(c);
    int r = atomicAdd(&lc[b], 1);  // LDS atomic: rank within (block, bucket)
    int rank = base2d[b * NBLK + blockIdx.x] + r;
    perm[rank] = n;
    irank[n] = rank;
    cntr[rank] = round8(c);
    craw[rank] = c;
  }
}

// ---- rank-space CSR offsets: exclusive scan of padded counts ----

__global__ void k_scan1(const int* __restrict__ cntr, int* __restrict__ incl,
                        int* __restrict__ bsum) {
  __shared__ int s[256];
  int t = threadIdx.x, i = blockIdx.x * 256 + t;
  s[t] = (i < NN) ? cntr[i] : 0;
  for (int off = 1; off < 256; off <<= 1) {
    __syncthreads();
    int u = (t >= off) ? s[t - off] : 0;
    __syncthreads();
    s[t] += u;
  }
  if (i < NN) incl[i] = s[t];
  if (t == 255) bsum[blockIdx.x] = s[255];
}

__global__ void k_scan2(int* __restrict__ bsum) {
  __shared__ int s[256];
  int t = threadIdx.x;
  int v = (t < NBLK) ? bsum[t] : 0;
  s[t] = v;
  for (int off = 1; off < 256; off <<= 1) {
    __syncthreads();
    int u = (t >= off) ? s[t - off] : 0;
    __syncthreads();
    s[t] += u;
  }
  if (t < NBLK) bsum[t] = s[t] - v;  // exclusive block offsets
}

__global__ void k_scan3(const int* __restrict__ cntr, int* __restrict__ offs,
                        const int* __restrict__ bsum) {
  int t = threadIdx.x, i = blockIdx.x * 256 + t;
  if (i < NN) offs[i] = offs[i] - cntr[i] + bsum[blockIdx.x];  // incl -> excl + base
}

// atomic-free CSR fill in RANK space: srcs stores source RANK (u16)
__global__ void k_fill(const int* __restrict__ ei, const float* __restrict__ ew,
                       const int* __restrict__ offs_r, const int* __restrict__ irank,
                       const u16* __restrict__ my_slot,
                       u16* __restrict__ srcs, float* __restrict__ wts) {
  int e = blockIdx.x * 256 + threadIdx.x;
  if (e < NE) {
    int r = ei[e], c = ei[NE + e];
    int slot = offs_r[irank[c]] + (int)my_slot[e];
    srcs[slot] = (u16)irank[r];
    wts[slot] = ew[e];
  }
}

// fill pad slots with (src=0, w=0) — weight 0 => contributes nothing downstream
__global__ void k_pad(const int* __restrict__ craw, const int* __restrict__ cntr,
                      const int* __restrict__ offs_r,
                      u16* __restrict__ srcs, float* __restrict__ wts) {
  int i = blockIdx.x * 256 + threadIdx.x;
  if (i < NN) {
    int base = offs_r[i];
    for (int j = base + craw[i]; j < base + cntr[i]; ++j) { srcs[j] = 0; wts[j] = 0.f; }
  }
}

// dinv_r[rank] = rsqrt(1 + sum of in-edge weights); contiguous rank streaming
__global__ void k_deg(const int* __restrict__ offs_r, const int* __restrict__ cntr,
                      const float* __restrict__ wts, float* __restrict__ dinv_r) {
  int i = blockIdx.x * 256 + threadIdx.x;
  if (i < NN) {
    int s = offs_r[i], e = s + cntr[i];
    float d0 = 1.0f, d1 = 0.f, d2 = 0.f, d3 = 0.f;  // self-loop weight 1
    for (int j = s; j < e; j += 4) {
      d0 += wts[j]; d1 += wts[j + 1]; d2 += wts[j + 2]; d3 += wts[j + 3];
    }
    dinv_r[i] = 1.0f / sqrtf((d0 + d1) + (d2 + d3));  // >= 1 always
  }
}

// wts[j] = dinv_r[src_rank] * ew * dinv_r[dst_rank]  (pads stay 0)
__global__ void k_scale(const int* __restrict__ offs_r, const int* __restrict__ cntr,
                        const float* __restrict__ dinv_r,
                        const u16* __restrict__ srcs, float* __restrict__ wts) {
  int i = blockIdx.x * 256 + threadIdx.x;
  if (i < NN) {
    int s = offs_r[i], e = s + cntr[i];
    float dn = dinv_r[i];
    for (int j = s; j < e; j += 4) {
      int s0 = srcs[j], s1 = srcs[j + 1], s2 = srcs[j + 2], s3 = srcs[j + 3];
      float v0 = dinv_r[s0], v1 = dinv_r[s1], v2 = dinv_r[s2], v3 = dinv_r[s3];
      wts[j]     = v0 * wts[j] * dn;
      wts[j + 1] = v1 * wts[j + 1] * dn;
      wts[j + 2] = v2 * wts[j + 2] * dn;
      wts[j + 3] = v3 * wts[j + 3] * dn;
    }
  }
}

// ---------------- GEMM: Yh[4][NN][32] (fp16, 64B rows) = X @ W ----------------
// PERM_DENSE: X dense node-space [NN][K], row via perm (layer 1).
// else: X = sliced rank-space H [4][NN][24] fp32 (layers 2,3).
// thread cg owns 12 features: slice = cg>>1, part = cg&1 (features slice*24+part*12..).

template <int K, bool PERM_DENSE>
__global__ __launch_bounds__(128) void k_gemm(const float* __restrict__ X,
                                              const float* __restrict__ Wg,
                                              _Float16* __restrict__ Yh,
                                              const int* __restrict__ perm) {
  constexpr int KC  = 32;
  constexpr int LDX = KC + 1;  // stride-33 rows -> conflict-free x reads
  __shared__ float sX[64 * LDX];
  __shared__ float sW[KC * CH];
  __shared__ int sPerm[64];
  int tid = threadIdx.x;
  int n0 = blockIdx.x * 64;
  int a = tid >> 3, cg = tid & 7;
  if (PERM_DENSE && tid < 64) {
    int nr = n0 + tid;
    sPerm[tid] = (nr < NN) ? perm[nr] : -1;
  }
  float acc[4][12];
#pragma unroll
  for (int j = 0; j < 4; ++j)
#pragma unroll
    for (int i = 0; i < 12; ++i) acc[j][i] = 0.f;

  for (int kc = 0; kc < K; kc += KC) {
    __syncthreads();  // protects prev-chunk LDS reads and sPerm store
    {
      const float4* src = (const float4*)(Wg + (size_t)kc * CH);
      float4* dst = (float4*)sW;
#pragma unroll
      for (int i = 0; i < 6; ++i) dst[tid + i * 128] = src[tid + i * 128];
    }
    {
#pragma unroll
      for (int p = 0; p < 4; ++p) {
        int i = tid + p * 128;
        int r = i >> 3, c = i & 7;
        float4 v = make_float4(0.f, 0.f, 0.f, 0.f);
        if (PERM_DENSE) {
          int row = sPerm[r];
          if (row >= 0) v = *(const float4*)(X + (size_t)row * K + kc + c * 4);
        } else {
          int n = n0 + r;
          if (n < NN) {
            int qq = (kc >> 2) + c;          // global float4 index 0..23
            int sl = qq / 6, part = qq - sl * 6;
            v = *(const float4*)(X + ((size_t)sl * NN + n) * 24 + part * 4);
          }
        }
        float* d = &sX[r * LDX + c * 4];
        d[0] = v.x; d[1] = v.y; d[2] = v.z; d[3] = v.w;
      }
    }
    __syncthreads();
#pragma unroll 8
    for (int k = 0; k < KC; ++k) {
      float xv[4];
#pragma unroll
      for (int j = 0; j < 4; ++j) xv[j] = sX[(a + j * 16) * LDX + k];
      const float4* wr = (const float4*)&sW[k * CH + cg * 12];
      float4 w0 = wr[0], w1 = wr[1], w2 = wr[2];
#pragma unroll
      for (int j = 0; j < 4; ++j) {
        acc[j][0] += xv[j] * w0.x; acc[j][1]  += xv[j] * w0.y;
        acc[j][2] += xv[j] * w0.z; acc[j][3]  += xv[j] * w0.w;
        acc[j][4] += xv[j] * w1.x; acc[j][5]  += xv[j] * w1.y;
        acc[j][6] += xv[j] * w1.z; acc[j][7]  += xv[j] * w1.w;
        acc[j][8] += xv[j] * w2.x; acc[j][9]  += xv[j] * w2.y;
        acc[j][10] += xv[j] * w2.z; acc[j][11] += xv[j] * w2.w;
      }
    }
  }
#pragma unroll
  for (int j = 0; j < 4; ++j) {
    int n = n0 + a + j * 16;  // rank
    if (n < NN) {
      _Float16* yo = Yh + ((size_t)(cg >> 1) * NN + n) * 32 + (cg & 1) * 12;
      half4 h0, h1, h2;
#pragma unroll
      for (int i = 0; i < 4; ++i) {
        h0[i] = (_Float16)acc[j][i];
        h1[i] = (_Float16)acc[j][i + 4];
        h2[i] = (_Float16)acc[j][i + 8];
      }
      *(half4*)(yo + 0) = h0;   // 8B stores, 8B-aligned (64n + 24*part + 8k)
      *(half4*)(yo + 4) = h1;
      *(half4*)(yo + 8) = h2;
    }
  }
}

// ---------------- aggregation (fp16 Y, 4 slices x 24 feats, 64B-line gathers) ----
// grid = 4 slices x 782 rank-blocks; slice = blockIdx & 3 -> XCDs {s, s+4}.
// Slice = 3.2MB -> L2-resident. 192 thr = 64 nodes x 3 lanes; each gather = one
// aligned 64B line (half8). Degree-sorted ranks: uniform trips, streaming CSR.

template <bool RELU>
__global__ __launch_bounds__(192) void k_agg(const _Float16* __restrict__ Yh,
                                             const int* __restrict__ offs_r,
                                             const int* __restrict__ cntr,
                                             const u16* __restrict__ srcs,
                                             const float* __restrict__ wts,
                                             const float* __restrict__ dinv_r,
                                             const float* __restrict__ bias,
                                             float* __restrict__ H) {
  int slice = blockIdx.x & 3;
  int nb = blockIdx.x >> 2;
  int tid = threadIdx.x;
  int nl = tid / 3;        // rank slot 0..63
  int fq = tid - nl * 3;   // half8 chunk 0..2 (8 features each)
  int n = nb * 64 + nl;    // rank
  if (n >= NN) return;
  const _Float16* Ys = Yh + (size_t)slice * NN * 32;
  float d = dinv_r[n];
  float sc = d * d;
  half8 sv = *(const half8*)(Ys + (size_t)n * 32 + fq * 8);
  float acc[8];
#pragma unroll
  for (int i = 0; i < 8; ++i) acc[i] = sc * (float)sv[i];
  int s = offs_r[n], e = s + cntr[n];  // multiple of 8, aligned starts
  for (int j = s; j < e; j += 8) {
    ushort8 s8 = *(const ushort8*)&srcs[j];
    float4 c0 = *(const float4*)&wts[j];
    float4 c1 = *(const float4*)&wts[j + 4];
    half8 yv[8];
#pragma unroll
    for (int u = 0; u < 8; ++u) yv[u] = *(const half8*)(Ys + (size_t)s8[u] * 32 + fq * 8);
    float cf[8] = {c0.x, c0.y, c0.z, c0.w, c1.x, c1.y, c1.z, c1.w};
#pragma unroll
    for (int u = 0; u < 8; ++u)
#pragma unroll
      for (int i = 0; i < 8; ++i) acc[i] += cf[u] * (float)yv[u][i];
  }
  const float* bp = bias + slice * 24 + fq * 8;
  float4 b0 = *(const float4*)bp, b1 = *(const float4*)(bp + 4);
  acc[0] += b0.x; acc[1] += b0.y; acc[2] += b0.z; acc[3] += b0.w;
  acc[4] += b1.x; acc[5] += b1.y; acc[6] += b1.z; acc[7] += b1.w;
  if (RELU) {
#pragma unroll
    for (int i = 0; i < 8; ++i) acc[i] = fmaxf(acc[i], 0.f);
  }
  float* hp = H + ((size_t)slice * NN + n) * 24 + fq * 8;
  *(float4*)hp = make_float4(acc[0], acc[1], acc[2], acc[3]);
  *(float4*)(hp + 4) = make_float4(acc[4], acc[5], acc[6], acc[7]);
}

// ---------------- pool + MLP ----------------

__global__ void k_gstart(const int* __restrict__ batch, int* __restrict__ gstart) {
  int i = blockIdx.x * 256 + threadIdx.x;
  if (i < NN) {
    int g = batch[i];
    if (i == 0 || batch[i - 1] != g) gstart[g] = i;
    if (i == NN - 1) gstart[NG] = NN;
  }
}

// H sliced rank-space [4][NN][24]: feature f of node n at H[(f/24)*NN+irank[n]]*24+f%24
__global__ void k_pool(const float* __restrict__ H, const int* __restrict__ gstart,
                       const int* __restrict__ irank, float* __restrict__ part) {
  int g = blockIdx.x, q = blockIdx.y, f = threadIdx.x;
  if (f >= CH) return;
  const float* Hf = H + (size_t)(f / 24) * NN * 24 + (f % 24);
  int s = gstart[g], e = gstart[g + 1];
  int len = e - s;
  int a = s + (int)(((long long)len * q) / 4);
  int b = s + (int)(((long long)len * (q + 1)) / 4);
  float m = -INFINITY;
  for (int n = a; n < b; ++n) m = fmaxf(m, Hf[(size_t)irank[n] * 24]);
  part[(g * 4 + q) * CH + f] = m;
}

__global__ void k_mlp(const float* __restrict__ part, const float* __restrict__ Wl1,
                      const float* __restrict__ bl1, const float* __restrict__ Wl2,
                      const float* __restrict__ bl2, float* __restrict__ out) {
  __shared__ float p[CH];
  __shared__ float hs[LH];
  int g = blockIdx.x, t = threadIdx.x;
  if (t < CH) {
    float m = part[(g * 4 + 0) * CH + t];
    m = fmaxf(m, part[(g * 4 + 1) * CH + t]);
    m = fmaxf(m, part[(g * 4 + 2) * CH + t]);
    m = fmaxf(m, part[(g * 4 + 3) * CH + t]);
    p[t] = fmaxf(m, 0.f);  // relu(max) == max(relu)
  }
  __syncthreads();
  if (t < LH) {
    float a = bl1[t];
#pragma unroll 4
    for (int k = 0; k < CH; ++k) a += p[k] * Wl1[k * LH + t];
    hs[t] = fmaxf(a, 0.f);
  }
  __syncthreads();
  if (t < NC) {
    float a = bl2[t];
#pragma unroll 4
    for (int k = 0; k < LH; ++k) a += hs[k] * Wl2[k * NC + t];
    out[g * NC + t] = a;
  }
}

}  // namespace

extern "C" void kernel_launch(void* const* d_in, const int* in_sizes, int n_in,
                              void* d_out, int out_size, void* d_ws, size_t ws_size,
                              hipStream_t stream) {
  const float* x   = (const float*)d_in[0];
  const int*   ei  = (const int*)d_in[1];
  const float* ew  = (const float*)d_in[2];
  const int*   bat = (const int*)d_in[3];
  const float* W1  = (const float*)d_in[4];
  const float* b1  = (const float*)d_in[5];
  const float* W2  = (const float*)d_in[6];
  const float* b2  = (const float*)d_in[7];
  const float* W3  = (const float*)d_in[8];
  const float* b3  = (const float*)d_in[9];
  const float* Wl1 = (const float*)d_in[10];
  const float* bl1 = (const float*)d_in[11];
  const float* Wl2 = (const float*)d_in[12];
  const float* bl2 = (const float*)d_in[13];
  float* out = (float*)d_out;

  // workspace carve-up (256B aligned)
  char* base = (char*)d_ws;
  size_t o = 0;
  auto carve = [&](size_t bytes) {
    char* p = base + o;
    o = (o + bytes + 255) & ~(size_t)255;
    return p;
  };
  constexpr size_t NEP = (size_t)NE + 8 * (size_t)NN;  // padded CSR capacity
  int*   cnt     = (int*)carve(NN * 4);
  u16*   my_slot = (u16*)carve((size_t)NE * 2);
  int*   hist2d  = (int*)carve(64 * NBLK * 4);
  int*   perm    = (int*)carve(NN * 4);
  int*   irank   = (int*)carve(NN * 4);
  int*   cntr    = (int*)carve(NN * 4);
  int*   craw    = (int*)carve(NN * 4);
  int*   offs_r  = (int*)carve(NN * 4);
  int*   bsum    = (int*)carve(256 * 4);
  float* dinv_r  = (float*)carve(NN * 4);
  int*   gstart  = (int*)carve((NG + 1) * 4);
  float* part    = (float*)carve(NG * 4 * CH * 4);
  u16*   srcs    = (u16*)carve(NEP * 2);
  float* wts     = (float*)carve(NEP * 4);
  _Float16* Yh   = (_Float16*)carve((size_t)4 * NN * 32 * 2);  // [4][NN][32] fp16
  float* H       = (float*)carve((size_t)4 * NN * 24 * 4);     // [4][NN][24] fp32
  (void)ws_size; (void)n_in; (void)in_sizes; (void)out_size;

  const int GB_N = NBLK;                     // 196
  const int GB_E = (NE + 255) / 256;         // 3125
  const int GB_G = (NN + 63) / 64;           // 782 gemm blocks
  const int GB_A = 4 * ((NN + 63) / 64);     // 4 slices x 782 rank-blocks

  // graph structure (shared by all 3 conv layers)
  k_init<<<GB_N, 256, 0, stream>>>(cnt);
  k_count<<<GB_E, 256, 0, stream>>>(ei, cnt, my_slot);
  // degree-bucket counting sort (no contended global atomics)
  k_bhist<<<GB_N, 256, 0, stream>>>(cnt, hist2d);
  k_gscan<<<1, 256, 0, stream>>>(hist2d);
  k_place<<<GB_N, 256, 0, stream>>>(cnt, hist2d, perm, irank, cntr, craw);
  // rank-space CSR
  k_scan1<<<GB_N, 256, 0, stream>>>(cntr, offs_r, bsum);
  k_scan2<<<1, 256, 0, stream>>>(bsum);
  k_scan3<<<GB_N, 256, 0, stream>>>(cntr, offs_r, bsum);
  k_fill<<<GB_E, 256, 0, stream>>>(ei, ew, offs_r, irank, my_slot, srcs, wts);
  k_pad<<<GB_N, 256, 0, stream>>>(craw, cntr, offs_r, srcs, wts);
  // normalization coefficients (rank space)
  k_deg<<<GB_N, 256, 0, stream>>>(offs_r, cntr, wts, dinv_r);
  k_scale<<<GB_N, 256, 0, stream>>>(offs_r, cntr, dinv_r, srcs, wts);

  // layer 1 (dense node-space input x, perm-gathered)
  k_gemm<FIN, true><<<GB_G, 128, 0, stream>>>(x, W1, Yh, perm);
  k_agg<true><<<GB_A, 192, 0, stream>>>(Yh, offs_r, cntr, srcs, wts, dinv_r, b1, H);
  // layer 2 (sliced rank-space input H)
  k_gemm<CH, false><<<GB_G, 128, 0, stream>>>(H, W2, Yh, perm);
  k_agg<true><<<GB_A, 192, 0, stream>>>(Yh, offs_r, cntr, srcs, wts, dinv_r, b2, H);
  // layer 3
  k_gemm<CH, false><<<GB_G, 128, 0, stream>>>(H, W3, Yh, perm);
  k_agg<false><<<GB_A, 192, 0, stream>>>(Yh, offs_r, cntr, srcs, wts, dinv_r, b3, H);

  // pool + MLP
  k_gstart<<<GB_N, 256, 0, stream>>>(bat, gstart);
  k_pool<<<dim3(NG, 4), 128, 0, stream>>>(H, gstart, irank, part);
  k_mlp<<<NG, 128, 0, stream>>>(part, Wl1, bl1, Wl2, bl2, out);
}

// Round 11
// 298.782 us; speedup vs baseline: 3.8943x; 1.0572x over previous
//
#include <hip/hip_runtime.h>
#include <math.h>

namespace {

constexpr int NN  = 50000;   // nodes
constexpr int NE  = 800000;  // edges
constexpr int FIN = 128;     // in features
constexpr int CH  = 96;      // conv hidden
constexpr int LH  = 64;      // lin hidden
constexpr int NC  = 10;      // classes
constexpr int NG  = 128;     // graphs
constexpr int NBLK = (NN + 255) / 256;  // 196 blocks over nodes

typedef unsigned short u16;
typedef __attribute__((ext_vector_type(8))) unsigned short ushort8;
typedef __attribute__((ext_vector_type(2))) _Float16 half2v;
typedef __attribute__((ext_vector_type(8))) _Float16 half8;

__device__ __forceinline__ int round8(int c) { return (c + 7) & ~7; }
__device__ __forceinline__ int bucket_of(int craw) { return min(round8(craw) >> 3, 63); }

// ---------------- graph-structure build (once per call) ----------------

__global__ void k_init(int* __restrict__ cnt) {
  int i = blockIdx.x * 256 + threadIdx.x;
  if (i < NN) cnt[i] = 0;
}

// one int atomic per edge; remember the slot so k_fill needs no atomic
__global__ void k_count(const int* __restrict__ ei, int* __restrict__ cnt,
                        u16* __restrict__ my_slot) {
  int e = blockIdx.x * 256 + threadIdx.x;
  if (e < NE) {
    int c = ei[NE + e];  // col (destination)
    my_slot[e] = (u16)atomicAdd(&cnt[c], 1);
  }
}

// ---- contention-free degree-bucket counting sort (rank = sorted position) ----

__global__ void k_bhist(const int* __restrict__ cnt, int* __restrict__ hist2d) {
  __shared__ int lh[64];
  int t = threadIdx.x;
  if (t < 64) lh[t] = 0;
  __syncthreads();
  int n = blockIdx.x * 256 + t;
  if (n < NN) atomicAdd(&lh[bucket_of(cnt[n])], 1);  // LDS atomic
  __syncthreads();
  if (t < 64) hist2d[t * NBLK + blockIdx.x] = lh[t];
}

// exclusive scan of hist2d[64*NBLK] in place; 64*196 = 12544 = 256*49
__global__ void k_gscan(int* __restrict__ h) {
  __shared__ int s[256];
  constexpr int CHUNK = (64 * NBLK) / 256;  // 49
  int t = threadIdx.x;
  int base = t * CHUNK;
  int sum = 0;
  for (int i = 0; i < CHUNK; ++i) sum += h[base + i];
  s[t] = sum;
  for (int off = 1; off < 256; off <<= 1) {
    __syncthreads();
    int u = (t >= off) ? s[t - off] : 0;
    __syncthreads();
    s[t] += u;
  }
  __syncthreads();
  int run = s[t] - sum;  // exclusive base for this chunk
  for (int i = 0; i < CHUNK; ++i) {
    int v = h[base + i];
    h[base + i] = run;
    run += v;
  }
}

__global__ void k_place(const int* __restrict__ cnt, const int* __restrict__ base2d,
                        int* __restrict__ perm, int* __restrict__ irank,
                        int* __restrict__ cntr, int* __restrict__ craw) {
  __shared__ int lc[64];
  int t = threadIdx.x;
  if (t < 64) lc[t] = 0;
  __syncthreads();
  int n = blockIdx.x * 256 + t;
  if (n < NN) {
    int c = cnt[n];
    int b = bucket_of(c);
    int r = atomicAdd(&lc[b], 1);  // LDS atomic: rank within (block, bucket)
    int rank = base2d[b * NBLK + blockIdx.x] + r;
    perm[rank] = n;
    irank[n] = rank;
    cntr[rank] = round8(c);
    craw[rank] = c;
  }
}

// ---- rank-space CSR offsets: exclusive scan of padded counts ----

__global__ void k_scan1(const int* __restrict__ cntr, int* __restrict__ incl,
                        int* __restrict__ bsum) {
  __shared__ int s[256];
  int t = threadIdx.x, i = blockIdx.x * 256 + t;
  s[t] = (i < NN) ? cntr[i] : 0;
  for (int off = 1; off < 256; off <<= 1) {
    __syncthreads();
    int u = (t >= off) ? s[t - off] : 0;
    __syncthreads();
    s[t] += u;
  }
  if (i < NN) incl[i] = s[t];
  if (t == 255) bsum[blockIdx.x] = s[255];
}

__global__ void k_scan2(int* __restrict__ bsum) {
  __shared__ int s[256];
  int t = threadIdx.x;
  int v = (t < NBLK) ? bsum[t] : 0;
  s[t] = v;
  for (int off = 1; off < 256; off <<= 1) {
    __syncthreads();
    int u = (t >= off) ? s[t - off] : 0;
    __syncthreads();
    s[t] += u;
  }
  if (t < NBLK) bsum[t] = s[t] - v;  // exclusive block offsets
}

__global__ void k_scan3(const int* __restrict__ cntr, int* __restrict__ offs,
                        const int* __restrict__ bsum) {
  int t = threadIdx.x, i = blockIdx.x * 256 + t;
  if (i < NN) offs[i] = offs[i] - cntr[i] + bsum[blockIdx.x];  // incl -> excl + base
}

// atomic-free CSR fill: ONE aligned 8B store per edge (src rank, raw weight)
__global__ void k_fill(const int* __restrict__ ei, const float* __restrict__ ew,
                       const int* __restrict__ offs_r, const int* __restrict__ irank,
                       const u16* __restrict__ my_slot, int2* __restrict__ epack) {
  int e = blockIdx.x * 256 + threadIdx.x;
  if (e < NE) {
    int r = ei[e], c = ei[NE + e];
    int slot = offs_r[irank[c]] + (int)my_slot[e];
    epack[slot] = make_int2(irank[r], __float_as_int(ew[e]));
  }
}

// fill pad slots with (src=0, w=0) — weight 0 => contributes nothing downstream
__global__ void k_pad(const int* __restrict__ craw, const int* __restrict__ cntr,
                      const int* __restrict__ offs_r, int2* __restrict__ epack) {
  int i = blockIdx.x * 256 + threadIdx.x;
  if (i < NN) {
    int base = offs_r[i];
    for (int j = base + craw[i]; j < base + cntr[i]; ++j) epack[j] = make_int2(0, 0);
  }
}

// dinv_r[rank] = rsqrt(1 + sum of in-edge weights); contiguous rank streaming
__global__ void k_deg(const int* __restrict__ offs_r, const int* __restrict__ cntr,
                      const int2* __restrict__ epack, float* __restrict__ dinv_r) {
  int i = blockIdx.x * 256 + threadIdx.x;
  if (i < NN) {
    int s = offs_r[i], e = s + cntr[i];
    float d0 = 1.0f, d1 = 0.f, d2 = 0.f, d3 = 0.f;  // self-loop weight 1
    for (int j = s; j < e; j += 4) {
      d0 += __int_as_float(epack[j].y);
      d1 += __int_as_float(epack[j + 1].y);
      d2 += __int_as_float(epack[j + 2].y);
      d3 += __int_as_float(epack[j + 3].y);
    }
    dinv_r[i] = 1.0f / sqrtf((d0 + d1) + (d2 + d3));  // >= 1 always
  }
}

// stream epack -> srcs (u16) + final coefficients wts (f32); full-line writes
__global__ void k_scale(const int* __restrict__ offs_r, const int* __restrict__ cntr,
                        const float* __restrict__ dinv_r,
                        const int2* __restrict__ epack,
                        u16* __restrict__ srcs, float* __restrict__ wts) {
  int i = blockIdx.x * 256 + threadIdx.x;
  if (i < NN) {
    int s = offs_r[i], e = s + cntr[i];
    float dn = dinv_r[i];
    for (int j = s; j < e; j += 4) {
      int2 p0 = epack[j], p1 = epack[j + 1], p2 = epack[j + 2], p3 = epack[j + 3];
      float v0 = dinv_r[p0.x], v1 = dinv_r[p1.x], v2 = dinv_r[p2.x], v3 = dinv_r[p3.x];
      srcs[j]     = (u16)p0.x; srcs[j + 1] = (u16)p1.x;
      srcs[j + 2] = (u16)p2.x; srcs[j + 3] = (u16)p3.x;
      wts[j]     = v0 * __int_as_float(p0.y) * dn;
      wts[j + 1] = v1 * __int_as_float(p1.y) * dn;
      wts[j + 2] = v2 * __int_as_float(p2.y) * dn;
      wts[j + 3] = v3 * __int_as_float(p3.y) * dn;
    }
  }
}

// ---------------- GEMM: Yh[4][NN][32] (fp16, 64B rows) = X @ W ----------------
// 256 threads, 64-node tile: a = tid>>4 (4 nodes a,a+16,a+32,a+48), cg = tid&15
// (6 cols each). 4 waves/block for occupancy. PERM_DENSE: X dense node-space via
// perm (layer 1); else X = sliced rank-space H [4][NN][24] fp32 (layers 2,3).

template <int K, bool PERM_DENSE>
__global__ __launch_bounds__(256) void k_gemm(const float* __restrict__ X,
                                              const float* __restrict__ Wg,
                                              _Float16* __restrict__ Yh,
                                              const int* __restrict__ perm) {
  constexpr int KC  = 32;
  constexpr int LDX = KC + 1;  // stride-33 rows -> conflict-free x reads
  __shared__ float sX[64 * LDX];
  __shared__ float sW[KC * CH];
  __shared__ int sPerm[64];
  int tid = threadIdx.x;
  int n0 = blockIdx.x * 64;
  int a = tid >> 4, cg = tid & 15;
  if (PERM_DENSE && tid < 64) {
    int nr = n0 + tid;
    sPerm[tid] = (nr < NN) ? perm[nr] : -1;
  }
  float acc[4][6];
#pragma unroll
  for (int j = 0; j < 4; ++j)
#pragma unroll
    for (int i = 0; i < 6; ++i) acc[j][i] = 0.f;

  for (int kc = 0; kc < K; kc += KC) {
    __syncthreads();  // protects prev-chunk LDS reads and sPerm store
    {
      const float4* src = (const float4*)(Wg + (size_t)kc * CH);
      float4* dst = (float4*)sW;
#pragma unroll
      for (int i = 0; i < 3; ++i) dst[tid + i * 256] = src[tid + i * 256];
    }
    {
#pragma unroll
      for (int p = 0; p < 2; ++p) {
        int i = tid + p * 256;
        int r = i >> 3, c = i & 7;
        float4 v = make_float4(0.f, 0.f, 0.f, 0.f);
        if (PERM_DENSE) {
          int row = sPerm[r];
          if (row >= 0) v = *(const float4*)(X + (size_t)row * K + kc + c * 4);
        } else {
          int n = n0 + r;
          if (n < NN) {
            int qq = (kc >> 2) + c;          // global float4 index 0..23
            int sl = qq / 6, part = qq - sl * 6;
            v = *(const float4*)(X + ((size_t)sl * NN + n) * 24 + part * 4);
          }
        }
        float* d = &sX[r * LDX + c * 4];
        d[0] = v.x; d[1] = v.y; d[2] = v.z; d[3] = v.w;
      }
    }
    __syncthreads();
#pragma unroll 8
    for (int k = 0; k < KC; ++k) {
      float xv[4];
#pragma unroll
      for (int j = 0; j < 4; ++j) xv[j] = sX[(a + j * 16) * LDX + k];
      const float2* wr = (const float2*)&sW[k * CH + cg * 6];
      float2 w0 = wr[0], w1 = wr[1], w2 = wr[2];
#pragma unroll
      for (int j = 0; j < 4; ++j) {
        acc[j][0] += xv[j] * w0.x; acc[j][1] += xv[j] * w0.y;
        acc[j][2] += xv[j] * w1.x; acc[j][3] += xv[j] * w1.y;
        acc[j][4] += xv[j] * w2.x; acc[j][5] += xv[j] * w2.y;
      }
    }
  }
  // epilogue: features cg*6..cg*6+5 -> slice cg>>2, in-slice offset (cg&3)*6
#pragma unroll
  for (int j = 0; j < 4; ++j) {
    int n = n0 + a + j * 16;  // rank
    if (n < NN) {
      _Float16* yo = Yh + ((size_t)(cg >> 2) * NN + n) * 32 + (cg & 3) * 6;
      half2v h0, h1, h2;
      h0[0] = (_Float16)acc[j][0]; h0[1] = (_Float16)acc[j][1];
      h1[0] = (_Float16)acc[j][2]; h1[1] = (_Float16)acc[j][3];
      h2[0] = (_Float16)acc[j][4]; h2[1] = (_Float16)acc[j][5];
      *(half2v*)(yo + 0) = h0;   // 4B stores, 4B-aligned (offset 12B-multiple)
      *(half2v*)(yo + 2) = h1;
      *(half2v*)(yo + 4) = h2;
    }
  }
}

// ---------------- aggregation (fp16 Y, 4 slices x 24 feats, 64B-line gathers) ----
// grid = 4 slices x 782 rank-blocks; slice = blockIdx & 3 -> XCDs {s, s+4}.
// Slice = 3.2MB -> L2-resident. 192 thr = 64 nodes x 3 lanes; each gather = one
// aligned 64B line (half8). Degree-sorted ranks: uniform trips, streaming CSR.

template <bool RELU>
__global__ __launch_bounds__(192) void k_agg(const _Float16* __restrict__ Yh,
                                             const int* __restrict__ offs_r,
                                             const int* __restrict__ cntr,
                                             const u16* __restrict__ srcs,
                                             const float* __restrict__ wts,
                                             const float* __restrict__ dinv_r,
                                             const float* __restrict__ bias,
                                             float* __restrict__ H) {
  int slice = blockIdx.x & 3;
  int nb = blockIdx.x >> 2;
  int tid = threadIdx.x;
  int nl = tid / 3;        // rank slot 0..63
  int fq = tid - nl * 3;   // half8 chunk 0..2 (8 features each)
  int n = nb * 64 + nl;    // rank
  if (n >= NN) return;
  const _Float16* Ys = Yh + (size_t)slice * NN * 32;
  float d = dinv_r[n];
  float sc = d * d;
  half8 sv = *(const half8*)(Ys + (size_t)n * 32 + fq * 8);
  float acc[8];
#pragma unroll
  for (int i = 0; i < 8; ++i) acc[i] = sc * (float)sv[i];
  int s = offs_r[n], e = s + cntr[n];  // multiple of 8, aligned starts
  for (int j = s; j < e; j += 8) {
    ushort8 s8 = *(const ushort8*)&srcs[j];
    float4 c0 = *(const float4*)&wts[j];
    float4 c1 = *(const float4*)&wts[j + 4];
    half8 yv[8];
#pragma unroll
    for (int u = 0; u < 8; ++u) yv[u] = *(const half8*)(Ys + (size_t)s8[u] * 32 + fq * 8);
    float cf[8] = {c0.x, c0.y, c0.z, c0.w, c1.x, c1.y, c1.z, c1.w};
#pragma unroll
    for (int u = 0; u < 8; ++u)
#pragma unroll
      for (int i = 0; i < 8; ++i) acc[i] += cf[u] * (float)yv[u][i];
  }
  const float* bp = bias + slice * 24 + fq * 8;
  float4 b0 = *(const float4*)bp, b1 = *(const float4*)(bp + 4);
  acc[0] += b0.x; acc[1] += b0.y; acc[2] += b0.z; acc[3] += b0.w;
  acc[4] += b1.x; acc[5] += b1.y; acc[6] += b1.z; acc[7] += b1.w;
  if (RELU) {
#pragma unroll
    for (int i = 0; i < 8; ++i) acc[i] = fmaxf(acc[i], 0.f);
  }
  float* hp = H + ((size_t)slice * NN + n) * 24 + fq * 8;
  *(float4*)hp = make_float4(acc[0], acc[1], acc[2], acc[3]);
  *(float4*)(hp + 4) = make_float4(acc[4], acc[5], acc[6], acc[7]);
}

// ---------------- pool + MLP ----------------

__global__ void k_gstart(const int* __restrict__ batch, int* __restrict__ gstart) {
  int i = blockIdx.x * 256 + threadIdx.x;
  if (i < NN) {
    int g = batch[i];
    if (i == 0 || batch[i - 1] != g) gstart[g] = i;
    if (i == NN - 1) gstart[NG] = NN;
  }
}

// H sliced rank-space [4][NN][24]: feature f of node n at H[(f/24)*NN+irank[n]]*24+f%24
__global__ void k_pool(const float* __restrict__ H, const int* __restrict__ gstart,
                       const int* __restrict__ irank, float* __restrict__ part) {
  int g = blockIdx.x, q = blockIdx.y, f = threadIdx.x;
  if (f >= CH) return;
  const float* Hf = H + (size_t)(f / 24) * NN * 24 + (f % 24);
  int s = gstart[g], e = gstart[g + 1];
  int len = e - s;
  int a = s + (int)(((long long)len * q) / 4);
  int b = s + (int)(((long long)len * (q + 1)) / 4);
  float m = -INFINITY;
  for (int n = a; n < b; ++n) m = fmaxf(m, Hf[(size_t)irank[n] * 24]);
  part[(g * 4 + q) * CH + f] = m;
}

__global__ void k_mlp(const float* __restrict__ part, const float* __restrict__ Wl1,
                      const float* __restrict__ bl1, const float* __restrict__ Wl2,
                      const float* __restrict__ bl2, float* __restrict__ out) {
  __shared__ float p[CH];
  __shared__ float hs[LH];
  int g = blockIdx.x, t = threadIdx.x;
  if (t < CH) {
    float m = part[(g * 4 + 0) * CH + t];
    m = fmaxf(m, part[(g * 4 + 1) * CH + t]);
    m = fmaxf(m, part[(g * 4 + 2) * CH + t]);
    m = fmaxf(m, part[(g * 4 + 3) * CH + t]);
    p[t] = fmaxf(m, 0.f);  // relu(max) == max(relu)
  }
  __syncthreads();
  if (t < LH) {
    float a = bl1[t];
#pragma unroll 4
    for (int k = 0; k < CH; ++k) a += p[k] * Wl1[k * LH + t];
    hs[t] = fmaxf(a, 0.f);
  }
  __syncthreads();
  if (t < NC) {
    float a = bl2[t];
#pragma unroll 4
    for (int k = 0; k < LH; ++k) a += hs[k] * Wl2[k * NC + t];
    out[g * NC + t] = a;
  }
}

}  // namespace

extern "C" void kernel_launch(void* const* d_in, const int* in_sizes, int n_in,
                              void* d_out, int out_size, void* d_ws, size_t ws_size,
                              hipStream_t stream) {
  const float* x   = (const float*)d_in[0];
  const int*   ei  = (const int*)d_in[1];
  const float* ew  = (const float*)d_in[2];
  const int*   bat = (const int*)d_in[3];
  const float* W1  = (const float*)d_in[4];
  const float* b1  = (const float*)d_in[5];
  const float* W2  = (const float*)d_in[6];
  const float* b2  = (const float*)d_in[7];
  const float* W3  = (const float*)d_in[8];
  const float* b3  = (const float*)d_in[9];
  const float* Wl1 = (const float*)d_in[10];
  const float* bl1 = (const float*)d_in[11];
  const float* Wl2 = (const float*)d_in[12];
  const float* bl2 = (const float*)d_in[13];
  float* out = (float*)d_out;

  // workspace carve-up (256B aligned)
  char* base = (char*)d_ws;
  size_t o = 0;
  auto carve = [&](size_t bytes) {
    char* p = base + o;
    o = (o + bytes + 255) & ~(size_t)255;
    return p;
  };
  constexpr size_t NEP = (size_t)NE + 8 * (size_t)NN;  // padded CSR capacity
  int*   cnt     = (int*)carve(NN * 4);
  u16*   my_slot = (u16*)carve((size_t)NE * 2);
  int*   hist2d  = (int*)carve(64 * NBLK * 4);
  int*   perm    = (int*)carve(NN * 4);
  int*   irank   = (int*)carve(NN * 4);
  int*   cntr    = (int*)carve(NN * 4);
  int*   craw    = (int*)carve(NN * 4);
  int*   offs_r  = (int*)carve(NN * 4);
  int*   bsum    = (int*)carve(256 * 4);
  float* dinv_r  = (float*)carve(NN * 4);
  int*   gstart  = (int*)carve((NG + 1) * 4);
  float* part    = (float*)carve(NG * 4 * CH * 4);
  int2*  epack   = (int2*)carve(NEP * 8);
  u16*   srcs    = (u16*)carve(NEP * 2);
  float* wts     = (float*)carve(NEP * 4);
  _Float16* Yh   = (_Float16*)carve((size_t)4 * NN * 32 * 2);  // [4][NN][32] fp16
  float* H       = (float*)carve((size_t)4 * NN * 24 * 4);     // [4][NN][24] fp32
  (void)ws_size; (void)n_in; (void)in_sizes; (void)out_size;

  const int GB_N = NBLK;                     // 196
  const int GB_E = (NE + 255) / 256;         // 3125
  const int GB_G = (NN + 63) / 64;           // 782 gemm blocks
  const int GB_A = 4 * ((NN + 63) / 64);     // 4 slices x 782 rank-blocks

  // graph structure (shared by all 3 conv layers)
  k_init<<<GB_N, 256, 0, stream>>>(cnt);
  k_count<<<GB_E, 256, 0, stream>>>(ei, cnt, my_slot);
  // degree-bucket counting sort (no contended global atomics)
  k_bhist<<<GB_N, 256, 0, stream>>>(cnt, hist2d);
  k_gscan<<<1, 256, 0, stream>>>(hist2d);
  k_place<<<GB_N, 256, 0, stream>>>(cnt, hist2d, perm, irank, cntr, craw);
  // rank-space CSR
  k_scan1<<<GB_N, 256, 0, stream>>>(cntr, offs_r, bsum);
  k_scan2<<<1, 256, 0, stream>>>(bsum);
  k_scan3<<<GB_N, 256, 0, stream>>>(cntr, offs_r, bsum);
  k_fill<<<GB_E, 256, 0, stream>>>(ei, ew, offs_r, irank, my_slot, epack);
  k_pad<<<GB_N, 256, 0, stream>>>(craw, cntr, offs_r, epack);
  // normalization coefficients (rank space) + stream-split to srcs/wts
  k_deg<<<GB_N, 256, 0, stream>>>(offs_r, cntr, epack, dinv_r);
  k_scale<<<GB_N, 256, 0, stream>>>(offs_r, cntr, dinv_r, epack, srcs, wts);

  // layer 1 (dense node-space input x, perm-gathered)
  k_gemm<FIN, true><<<GB_G, 256, 0, stream>>>(x, W1, Yh, perm);
  k_agg<true><<<GB_A, 192, 0, stream>>>(Yh, offs_r, cntr, srcs, wts, dinv_r, b1, H);
  // layer 2 (sliced rank-space input H)
  k_gemm<CH, false><<<GB_G, 256, 0, stream>>>(H, W2, Yh, perm);
  k_agg<true><<<GB_A, 192, 0, stream>>>(Yh, offs_r, cntr, srcs, wts, dinv_r, b2, H);
  // layer 3
  k_gemm<CH, false><<<GB_G, 256, 0, stream>>>(H, W3, Yh, perm);
  k_agg<false><<<GB_A, 192, 0, stream>>>(Yh, offs_r, cntr, srcs, wts, dinv_r, b3, H);

  // pool + MLP
  k_gstart<<<GB_N, 256, 0, stream>>>(bat, gstart);
  k_pool<<<dim3(NG, 4), 128, 0, stream>>>(H, gstart, irank, part);
  k_mlp<<<NG, 128, 0, stream>>>(part, Wl1, bl1, Wl2, bl2, out);
}